// Round 2
// baseline (193.149 us; speedup 1.0000x reference)
//
#include <hip/hip_runtime.h>
#include <cmath>

#define BATCH   32
#define CCH     512
#define HW      4096
#define KCL     17
#define TS      64        // pixels per tile
#define NT      8         // tiles per block (512 px per slice)
#define NTHREADS 512

// LDS layout (floats)
#define XOFF 0                       // x tile: 512 x 64
#define ROFF (CCH*TS)                // reduce buffer: 4*17*64
#define SOFF (ROFF + 4*KCL*64)       // sigT: 64 x 20
#define SMEM_FLOATS (SOFF + 64*20)   // = 32768 + 4352 + 1280 = 38400 floats = 153600 B

__global__ void zero_out_kernel(float* __restrict__ out, int n) {
  int i = blockIdx.x * blockDim.x + threadIdx.x;
  if (i < n) out[i] = 0.f;
}

__global__ void transpose_w_kernel(const float* __restrict__ w, float* __restrict__ wT) {
  int c = threadIdx.x;  // 512 threads
  #pragma unroll
  for (int k = 0; k < 20; ++k)
    wT[c * 20 + k] = (k < KCL) ? w[k * CCH + c] : 0.f;
}

template <bool USE_WT>
__global__ __launch_bounds__(NTHREADS, 2)
void ssam_fused(const float* __restrict__ x, const float* __restrict__ w,
                const float* __restrict__ bias, const float* __restrict__ wT,
                float* __restrict__ out_g, float* __restrict__ out_sf) {
  extern __shared__ float smem[];
  float* lx = smem + XOFF;
  float* R  = smem + ROFF;
  float* sT = smem + SOFF;

  const int t    = threadIdx.x;
  const int lane = t & 63;
  const int wv   = __builtin_amdgcn_readfirstlane(t >> 6);  // wave id, uniform
  const int b     = blockIdx.x >> 3;
  const int slice = blockIdx.x & 7;
  const size_t xbase = (size_t)b * CCH * HW;

  // phase-2 mapping: kq in 0..3 (k sets {0-3,4-7,8-11,12-16}), g in 0..127 -> c = g + 128*i
  const int kq    = t >> 7;
  const int g     = t & 127;
  const int kbase = kq * 4;
  const int nk    = (kq == 3) ? 5 : 4;

  float gacc[KCL];
  #pragma unroll
  for (int k = 0; k < KCL; ++k) gacc[k] = 0.f;
  float acc[5][4];
  #pragma unroll
  for (int a = 0; a < 5; ++a)
    #pragma unroll
    for (int i = 0; i < 4; ++i) acc[a][i] = 0.f;

  const int l_hi = lane >> 2;   // for phase-1 swizzled read
  const int l_lo = lane & 3;

  int cbase[4], swz[4];
  #pragma unroll
  for (int i = 0; i < 4; ++i) {
    int c = g + 128 * i;
    cbase[i] = c * 64;
    swz[i]   = c & 15;
  }

  for (int tile = 0; tile < NT; ++tile) {
    const int p0 = slice * (TS * NT) + tile * TS;

    // ---- stage x tile (512c x 64p) into LDS with slot swizzle J' = J ^ (c&15) ----
    #pragma unroll
    for (int j = 0; j < 16; ++j) {
      int m = t + NTHREADS * j;       // 0..8191 float4 chunks
      int c = m >> 4;                 // 16 float4 per row
      int J = m & 15;
      const float4 v = *reinterpret_cast<const float4*>(x + xbase + (size_t)c * HW + p0 + 4 * J);
      int Jp = J ^ (c & 15);
      *reinterpret_cast<float4*>(lx + c * 64 + 4 * Jp) = v;
    }
    __syncthreads();

    // ---- phase 1: cam partials; wave wv covers channels [64*wv, 64*wv+64), lane = pixel ----
    float cam[KCL];
    #pragma unroll
    for (int k = 0; k < KCL; ++k) cam[k] = 0.f;
    const int c0 = wv * 64;
    #pragma unroll 4
    for (int cc = 0; cc < 64; ++cc) {
      const int c = c0 + cc;
      const float xv = lx[c * 64 + 4 * (l_hi ^ (c & 15)) + l_lo];
      if (USE_WT) {
        #pragma unroll
        for (int k = 0; k < KCL; ++k) cam[k] = fmaf(wT[c * 20 + k], xv, cam[k]);
      } else {
        #pragma unroll
        for (int k = 0; k < KCL; ++k) cam[k] = fmaf(w[k * CCH + c], xv, cam[k]);
      }
    }

    // ---- reduce 8 wave partials (tree via LDS) ----
    if (wv >= 4) {
      #pragma unroll
      for (int k = 0; k < KCL; ++k) R[((wv - 4) * KCL + k) * 64 + lane] = cam[k];
    }
    __syncthreads();
    if (wv < 4) {
      #pragma unroll
      for (int k = 0; k < KCL; ++k) cam[k] += R[(wv * KCL + k) * 64 + lane];
    }
    __syncthreads();
    if (wv == 2 || wv == 3) {
      #pragma unroll
      for (int k = 0; k < KCL; ++k) R[((wv - 2) * KCL + k) * 64 + lane] = cam[k];
    }
    __syncthreads();
    if (wv < 2) {
      #pragma unroll
      for (int k = 0; k < KCL; ++k) cam[k] += R[(wv * KCL + k) * 64 + lane];
    }
    __syncthreads();
    if (wv == 1) {
      #pragma unroll
      for (int k = 0; k < KCL; ++k) R[k * 64 + lane] = cam[k];
    }
    __syncthreads();
    if (wv == 0) {
      #pragma unroll
      for (int k = 0; k < KCL; ++k) {
        float cf = cam[k] + R[k * 64 + lane] + bias[k];
        gacc[k] += cf;                                    // g = mean(cam) by linearity
        sT[lane * 20 + k] = 1.f / (1.f + __expf(-cf));    // sigmoid
      }
    }
    __syncthreads();

    // ---- phase 2: sf accumulate, thread tile = (4|5 k) x (4 c) x (4 px per step) ----
    #pragma unroll 2
    for (int pg = 0; pg < 16; ++pg) {
      float4 xv[4];
      #pragma unroll
      for (int i = 0; i < 4; ++i)
        xv[i] = *reinterpret_cast<const float4*>(lx + cbase[i] + 4 * (pg ^ swz[i]));
      float4 sg[4];
      float s16[4];
      #pragma unroll
      for (int j = 0; j < 4; ++j) {
        sg[j] = *reinterpret_cast<const float4*>(sT + (4 * pg + j) * 20 + kbase);
        if (kq == 3) s16[j] = sT[(4 * pg + j) * 20 + 16];
      }
      #pragma unroll
      for (int j = 0; j < 4; ++j) {
        const float* sgj = reinterpret_cast<const float*>(&sg[j]);
        #pragma unroll
        for (int kk = 0; kk < 4; ++kk) {
          const float s = sgj[kk];
          #pragma unroll
          for (int i = 0; i < 4; ++i) {
            const float* xvi = reinterpret_cast<const float*>(&xv[i]);
            acc[kk][i] = fmaf(s, xvi[j], acc[kk][i]);
          }
        }
        if (kq == 3) {
          #pragma unroll
          for (int i = 0; i < 4; ++i) {
            const float* xvi = reinterpret_cast<const float*>(&xv[i]);
            acc[4][i] = fmaf(s16[j], xvi[j], acc[4][i]);
          }
        }
      }
    }
    __syncthreads();  // protect lx/sT before next tile's staging
  }

  // ---- epilogue ----
  const float inv = 1.f / 4096.f;
  #pragma unroll
  for (int kk = 0; kk < 5; ++kk) {
    if (kk < nk) {
      #pragma unroll
      for (int i = 0; i < 4; ++i) {
        atomicAdd(out_sf + (size_t)(b * KCL + kbase + kk) * CCH + (g + 128 * i),
                  acc[kk][i] * inv);
      }
    }
  }
  if (wv == 0) {
    #pragma unroll
    for (int k = 0; k < KCL; ++k) {
      float v = gacc[k];
      #pragma unroll
      for (int off = 1; off < 64; off <<= 1) v += __shfl_xor(v, off, 64);
      if (lane == 0) atomicAdd(out_g + b * KCL + k, v * inv);
    }
  }
}

extern "C" void kernel_launch(void* const* d_in, const int* in_sizes, int n_in,
                              void* d_out, int out_size, void* d_ws, size_t ws_size,
                              hipStream_t stream) {
  const float* x    = (const float*)d_in[0];
  const float* w    = (const float*)d_in[1];
  const float* bias = (const float*)d_in[2];
  float* out   = (float*)d_out;
  float* outg  = out;                // (32,17)
  float* outsf = out + BATCH * KCL;  // (32,17,512)
  float* wT = (float*)d_ws;

  const int total = BATCH * KCL + BATCH * KCL * CCH;  // 279072
  zero_out_kernel<<<(total + 511) / 512, 512, 0, stream>>>(out, total);

  const size_t smem = SMEM_FLOATS * sizeof(float);
  const bool use_wt = (d_ws != nullptr) && (ws_size >= 512 * 20 * sizeof(float));

  if (use_wt) {
    transpose_w_kernel<<<1, 512, 0, stream>>>(w, wT);
    hipFuncSetAttribute((const void*)ssam_fused<true>,
                        hipFuncAttributeMaxDynamicSharedMemorySize, (int)smem);
    ssam_fused<true><<<256, NTHREADS, smem, stream>>>(x, w, bias, wT, outg, outsf);
  } else {
    hipFuncSetAttribute((const void*)ssam_fused<false>,
                        hipFuncAttributeMaxDynamicSharedMemorySize, (int)smem);
    ssam_fused<false><<<256, NTHREADS, smem, stream>>>(x, w, bias, wT, outg, outsf);
  }
}